// Round 9
// baseline (2604.238 us; speedup 1.0000x reference)
//
#include <hip/hip_runtime.h>
#include <hip/hip_bf16.h>

#define DIMD 256
#define SEQ 196
#define BATCH 16
#define NST 64
#define NROWS (BATCH * SEQ) /* 3136 */

__device__ __forceinline__ float softplus_f(float x) {
    return fmaxf(x, 0.f) + log1pf(expf(-fabsf(x)));
}

/* ---------------- patch gather: x (B,3,224,224) -> xp (B,196,768) ---------------- */
__global__ __launch_bounds__(256) void gather_kernel(const float* __restrict__ x,
                                                     float* __restrict__ xp) {
    int i = blockIdx.x * 256 + threadIdx.x;
    if (i >= BATCH * SEQ * 768) return;
    int j = i % 768;
    int s = (i / 768) % SEQ;
    int b = i / (768 * SEQ);
    int c = j % 3;
    int p2 = (j / 3) % 16;
    int p1 = j / 48;
    int hp = s / 14, wp = s % 14;
    int hh = hp * 16 + p1, ww = wp * 16 + p2;
    xp[i] = x[((long)(b * 3 + c) * 224 + hh) * 224 + ww];
}

/* ---------------- generic f32 GEMM: C[m,n] = act(sum_k A[m,k]*W[n,k] + bias[n]) ----
   blockIdx.z selects operand set (for fwd/bwd direction pairs).
   BM=BN=64, BK=32, 256 threads, thread computes 4x4. M must be multiple of 64. */
#define BM 64
#define BN 64
#define BK 32

template <int ACT> /* 0 = none, 1 = softplus */
__global__ __launch_bounds__(256) void gemm_kernel(
    const float* __restrict__ A0, const float* __restrict__ A1, int lda,
    const float* __restrict__ W0, const float* __restrict__ W1,
    const float* __restrict__ b0, const float* __restrict__ b1,
    float* __restrict__ C0, float* __restrict__ C1, int ldc,
    int M, int N, int K) {
    const float* A = blockIdx.z ? A1 : A0;
    const float* W = blockIdx.z ? W1 : W0;
    const float* bias = blockIdx.z ? b1 : b0;
    float* C = blockIdx.z ? C1 : C0;

    __shared__ float As[BK][BM];
    __shared__ float Ws[BK][BN];

    const int tid = threadIdx.x;
    const int m0 = blockIdx.x * BM;
    const int n0 = blockIdx.y * BN;
    const int tx = tid & 15, ty = tid >> 4;
    const int lrow = tid >> 3;        /* 0..31 */
    const int lcol = (tid & 7) * 4;   /* 0..28 */

    float acc[4][4] = {};

    for (int k0 = 0; k0 < K; k0 += BK) {
#pragma unroll
        for (int h = 0; h < 2; ++h) {
            int m = lrow + h * 32;
            float4 v = *reinterpret_cast<const float4*>(&A[(long)(m0 + m) * lda + k0 + lcol]);
            As[lcol + 0][m] = v.x; As[lcol + 1][m] = v.y;
            As[lcol + 2][m] = v.z; As[lcol + 3][m] = v.w;
        }
#pragma unroll
        for (int h = 0; h < 2; ++h) {
            int n = lrow + h * 32;
            float4 v = make_float4(0.f, 0.f, 0.f, 0.f);
            if (n0 + n < N)
                v = *reinterpret_cast<const float4*>(&W[(long)(n0 + n) * K + k0 + lcol]);
            Ws[lcol + 0][n] = v.x; Ws[lcol + 1][n] = v.y;
            Ws[lcol + 2][n] = v.z; Ws[lcol + 3][n] = v.w;
        }
        __syncthreads();
#pragma unroll
        for (int k = 0; k < BK; ++k) {
            float4 a = *reinterpret_cast<const float4*>(&As[k][ty * 4]);
            float4 w = *reinterpret_cast<const float4*>(&Ws[k][tx * 4]);
            float av[4] = {a.x, a.y, a.z, a.w};
            float wv[4] = {w.x, w.y, w.z, w.w};
#pragma unroll
            for (int i = 0; i < 4; ++i)
#pragma unroll
                for (int j = 0; j < 4; ++j)
                    acc[i][j] = fmaf(av[i], wv[j], acc[i][j]);
        }
        __syncthreads();
    }

    float bv[4];
#pragma unroll
    for (int j = 0; j < 4; ++j) {
        int n = n0 + tx * 4 + j;
        bv[j] = (b0 != nullptr && n < N) ? bias[n] : 0.f;
    }
#pragma unroll
    for (int i = 0; i < 4; ++i) {
        int m = m0 + ty * 4 + i;
        int n = n0 + tx * 4;
        if (n + 3 < N) {
            float4 o;
            float v0 = acc[i][0] + bv[0], v1 = acc[i][1] + bv[1];
            float v2 = acc[i][2] + bv[2], v3 = acc[i][3] + bv[3];
            if (ACT == 1) { v0 = softplus_f(v0); v1 = softplus_f(v1);
                            v2 = softplus_f(v2); v3 = softplus_f(v3); }
            o.x = v0; o.y = v1; o.z = v2; o.w = v3;
            *reinterpret_cast<float4*>(&C[(long)m * ldc + n]) = o;
        } else {
#pragma unroll
            for (int j = 0; j < 4; ++j)
                if (n + j < N) {
                    float v = acc[i][j] + bv[j];
                    if (ACT == 1) v = softplus_f(v);
                    C[(long)m * ldc + n + j] = v;
                }
        }
    }
}

/* ---------------- LayerNorm over last dim (256), one wave per row ---------------- */
__global__ __launch_bounds__(256) void ln_kernel(const float* __restrict__ in,
                                                 float* __restrict__ out,
                                                 const float* __restrict__ g,
                                                 const float* __restrict__ b) {
    int wid = blockIdx.x * 4 + (threadIdx.x >> 6);
    int lane = threadIdx.x & 63;
    const float* row = in + (long)wid * DIMD;
    float4 v = *reinterpret_cast<const float4*>(&row[lane * 4]);
    float s = v.x + v.y + v.z + v.w;
    float q = v.x * v.x + v.y * v.y + v.z * v.z + v.w * v.w;
#pragma unroll
    for (int m = 32; m >= 1; m >>= 1) {
        s += __shfl_xor(s, m, 64);
        q += __shfl_xor(q, m, 64);
    }
    float mean = s * (1.f / 256.f);
    float var = q * (1.f / 256.f) - mean * mean;
    float rstd = rsqrtf(var + 1e-5f);
    float4 gv = *reinterpret_cast<const float4*>(&g[lane * 4]);
    float4 bv = *reinterpret_cast<const float4*>(&b[lane * 4]);
    float4 o;
    o.x = (v.x - mean) * rstd * gv.x + bv.x;
    o.y = (v.y - mean) * rstd * gv.y + bv.y;
    o.z = (v.z - mean) * rstd * gv.z + bv.z;
    o.w = (v.w - mean) * rstd * gv.w + bv.w;
    *reinterpret_cast<float4*>(&out[(long)wid * DIMD + lane * 4]) = o;
}

/* ---------------- selective scan: wave = (b,d), lane = state n ---------------- */
__global__ __launch_bounds__(256) void ssm_kernel(
    const float* __restrict__ xcA, const float* __restrict__ xcB,
    const float* __restrict__ dbcA, const float* __restrict__ dbcB,
    const float* __restrict__ deA, const float* __restrict__ deB,
    float* __restrict__ yA, float* __restrict__ yB,
    const float* __restrict__ A_log, const float* __restrict__ Dp) {
    const int dir = blockIdx.y;
    const float* xc = dir ? xcB : xcA;
    const float* dbc = dir ? dbcB : dbcA;
    const float* de = dir ? deB : deA;
    float* y = dir ? yB : yA;

    int w = blockIdx.x * 4 + (threadIdx.x >> 6); /* 0..4095 */
    int lane = threadIdx.x & 63;
    int b = w >> 8, d = w & 255;

    /* A2 = -exp(A_log) * log2(e) so that exp(delta*A) = exp2(delta*A2) */
    float A2 = -expf(A_log[d * NST + lane]) * 1.44269504088896341f;
    float Dv = Dp[d];

    const float* deRow = de + (long)b * SEQ * DIMD + d;
    const float* xcRow = xc + (long)b * SEQ * DIMD + d;
    const float* dbcRow = dbc + (long)b * SEQ * 160;
    float* yRow = y + (long)b * SEQ * DIMD + d;

    float h = 0.f;
#pragma unroll 4
    for (int s = 0; s < SEQ; ++s) {
        float du = deRow[(long)s * DIMD];
        float xu = xcRow[(long)s * DIMD];
        float Bn = dbcRow[(long)s * 160 + 32 + lane];
        float Cn = dbcRow[(long)s * 160 + 96 + lane];
        float e = exp2f(du * A2);
        h = fmaf(e, h, (du * xu) * Bn);
        float v = h * Cn;
#pragma unroll
        for (int m = 32; m >= 1; m >>= 1) v += __shfl_xor(v, m, 64);
        if (lane == 0) yRow[(long)s * DIMD] = v + Dv * xu;
    }
}

/* ---------------- combine + LN for next layer, one wave per row ---------------- */
__global__ __launch_bounds__(256) void combine_ln_kernel(
    const float* __restrict__ y1, const float* __restrict__ y2,
    const float* __restrict__ z, float* __restrict__ t,
    float* __restrict__ xn, const float* __restrict__ g,
    const float* __restrict__ b) {
    int wid = blockIdx.x * 4 + (threadIdx.x >> 6);
    int lane = threadIdx.x & 63;
    long base = (long)wid * DIMD + lane * 4;
    float4 a = *reinterpret_cast<const float4*>(&y1[base]);
    float4 c = *reinterpret_cast<const float4*>(&y2[base]);
    float4 zz = *reinterpret_cast<const float4*>(&z[base]);
    float4 tt = *reinterpret_cast<const float4*>(&t[base]);
    float4 tn;
    {
        float zs;
        zs = zz.x / (1.f + expf(-zz.x)); tn.x = (a.x + c.x) * zs + tt.x;
        zs = zz.y / (1.f + expf(-zz.y)); tn.y = (a.y + c.y) * zs + tt.y;
        zs = zz.z / (1.f + expf(-zz.z)); tn.z = (a.z + c.z) * zs + tt.z;
        zs = zz.w / (1.f + expf(-zz.w)); tn.w = (a.w + c.w) * zs + tt.w;
    }
    *reinterpret_cast<float4*>(&t[base]) = tn;
    float s = tn.x + tn.y + tn.z + tn.w;
    float q = tn.x * tn.x + tn.y * tn.y + tn.z * tn.z + tn.w * tn.w;
#pragma unroll
    for (int m = 32; m >= 1; m >>= 1) {
        s += __shfl_xor(s, m, 64);
        q += __shfl_xor(q, m, 64);
    }
    float mean = s * (1.f / 256.f);
    float var = q * (1.f / 256.f) - mean * mean;
    float rstd = rsqrtf(var + 1e-5f);
    float4 gv = *reinterpret_cast<const float4*>(&g[lane * 4]);
    float4 bv = *reinterpret_cast<const float4*>(&b[lane * 4]);
    float4 o;
    o.x = (tn.x - mean) * rstd * gv.x + bv.x;
    o.y = (tn.y - mean) * rstd * gv.y + bv.y;
    o.z = (tn.z - mean) * rstd * gv.z + bv.z;
    o.w = (tn.w - mean) * rstd * gv.w + bv.w;
    *reinterpret_cast<float4*>(&xn[base]) = o;
}

/* ---------------- head: pool + LN + linear(1000) + softmax, block per batch ----- */
__global__ __launch_bounds__(256) void head_kernel(
    const float* __restrict__ t, const float* __restrict__ hg,
    const float* __restrict__ hb, const float* __restrict__ hw,
    const float* __restrict__ hbias, float* __restrict__ out) {
    __shared__ float xh[DIMD];
    __shared__ float red[8];
    __shared__ float logits[1000];
    int b = blockIdx.x, tid = threadIdx.x;
    int wv = tid >> 6, ln = tid & 63;

    /* mean pool over S */
    float s = 0.f;
    const float* tb = t + (long)b * SEQ * DIMD;
    for (int si = 0; si < SEQ; ++si) s += tb[(long)si * DIMD + tid];
    s *= (1.f / (float)SEQ);

    /* LN over 256 across threads */
    float sum = s, sq = s * s;
#pragma unroll
    for (int m = 32; m >= 1; m >>= 1) {
        sum += __shfl_xor(sum, m, 64);
        sq += __shfl_xor(sq, m, 64);
    }
    if (ln == 0) { red[wv] = sum; red[4 + wv] = sq; }
    __syncthreads();
    float S = red[0] + red[1] + red[2] + red[3];
    float Q = red[4] + red[5] + red[6] + red[7];
    float mean = S * (1.f / 256.f);
    float var = Q * (1.f / 256.f) - mean * mean;
    float rstd = rsqrtf(var + 1e-5f);
    xh[tid] = (s - mean) * rstd * hg[tid] + hb[tid];
    __syncthreads();

    /* logits */
    for (int c = tid; c < 1000; c += 256) {
        float acc = hbias[c];
        const float* wr = hw + (long)c * DIMD;
        for (int k = 0; k < DIMD; k += 4) {
            float4 w4 = *reinterpret_cast<const float4*>(&wr[k]);
            acc += xh[k] * w4.x + xh[k + 1] * w4.y + xh[k + 2] * w4.z + xh[k + 3] * w4.w;
        }
        logits[c] = acc;
    }
    __syncthreads();

    /* softmax */
    float mx = -1e30f;
    for (int c = tid; c < 1000; c += 256) mx = fmaxf(mx, logits[c]);
#pragma unroll
    for (int m = 32; m >= 1; m >>= 1) mx = fmaxf(mx, __shfl_xor(mx, m, 64));
    if (ln == 0) red[wv] = mx;
    __syncthreads();
    mx = fmaxf(fmaxf(red[0], red[1]), fmaxf(red[2], red[3]));
    float se = 0.f;
    for (int c = tid; c < 1000; c += 256) {
        float e = expf(logits[c] - mx);
        logits[c] = e;
        se += e;
    }
#pragma unroll
    for (int m = 32; m >= 1; m >>= 1) se += __shfl_xor(se, m, 64);
    __syncthreads();
    if (ln == 0) red[4 + wv] = se;
    __syncthreads();
    se = red[4] + red[5] + red[6] + red[7];
    float inv = 1.f / se;
    for (int c = tid; c < 1000; c += 256)
        out[b * 1000 + c] = logits[c] * inv;
}

/* ============================== host launcher ============================== */
extern "C" void kernel_launch(void* const* d_in, const int* in_sizes, int n_in,
                              void* d_out, int out_size, void* d_ws, size_t ws_size,
                              hipStream_t stream) {
    const float* x       = (const float*)d_in[0];
    const float* patch_w = (const float*)d_in[1];
    const float* patch_b = (const float*)d_in[2];
    const float* norm_g  = (const float*)d_in[3];
    const float* norm_b  = (const float*)d_in[4];
    const float* proj_w  = (const float*)d_in[5];
    const float* proj_b  = (const float*)d_in[6];
    const float* fconv_w = (const float*)d_in[7];
    const float* fconv_b = (const float*)d_in[8];
    const float* bconv_w = (const float*)d_in[9];
    const float* bconv_b = (const float*)d_in[10];
    const float* dbc_w   = (const float*)d_in[11];
    const float* dt_w    = (const float*)d_in[12];
    const float* dt_b    = (const float*)d_in[13];
    const float* A_log   = (const float*)d_in[14];
    const float* Dp      = (const float*)d_in[15];
    const float* head_g  = (const float*)d_in[16];
    const float* head_b  = (const float*)d_in[17];
    const float* head_w  = (const float*)d_in[18];
    const float* head_bias = (const float*)d_in[19];
    float* out = (float*)d_out; /* reference output dtype is FLOAT32 (softmax of f32) */

    float* ws = (float*)d_ws;
    const long NTOK = (long)NROWS * DIMD; /* 802816 */
    float* t_buf  = ws;
    float* xn     = ws + NTOK;
    float* z      = ws + 2 * NTOK;
    float* delta1 = ws + 3 * NTOK;
    float* delta2 = ws + 4 * NTOK;
    float* y1     = ws + 5 * NTOK;
    float* y2     = ws + 6 * NTOK;
    float* dbc2   = ws + 7 * NTOK; /* 3136*160 = 501760 */
    float* xp     = ws + 7 * NTOK + 501760;
    float* xc1    = xp;            /* reuse xp region after patch embed */
    float* xc2    = xp + NTOK;
    float* dbc1   = xp + 2 * NTOK; /* 501760, fits inside xp (2408448) */

    /* patch embed */
    gather_kernel<<<(BATCH * SEQ * 768 + 255) / 256, 256, 0, stream>>>(x, xp);
    gemm_kernel<0><<<dim3(49, 4, 1), 256, 0, stream>>>(
        xp, xp, 768, patch_w, patch_w, patch_b, patch_b, t_buf, t_buf, 256,
        NROWS, 256, 768);

    ln_kernel<<<NROWS / 4, 256, 0, stream>>>(t_buf, xn, norm_g, norm_b);

    for (int L = 0; L < 12; ++L) {
        const float* pw  = proj_w + (long)L * 256 * 256;
        const float* pb  = proj_b + (long)L * 256;
        const float* fw  = fconv_w + (long)L * 256 * 256;
        const float* fb  = fconv_b + (long)L * 256;
        const float* bw  = bconv_w + (long)L * 256 * 256;
        const float* bb  = bconv_b + (long)L * 256;
        const float* dw  = dbc_w + (long)L * 160 * 256;
        const float* tw  = dt_w + (long)L * 256 * 32;
        const float* tb  = dt_b + (long)L * 256;
        const float* Al  = A_log + (long)L * 256 * 64;
        const float* Dl  = Dp + (long)L * 256;
        int Ln = (L + 1) % 12;
        const float* ng = norm_g + (long)Ln * 256;
        const float* nb = norm_b + (long)Ln * 256;

        /* z = xn @ proj^T + pb */
        gemm_kernel<0><<<dim3(49, 4, 1), 256, 0, stream>>>(
            xn, xn, 256, pw, pw, pb, pb, z, z, 256, NROWS, 256, 256);
        /* xc = softplus(z @ conv^T + cb), both directions */
        gemm_kernel<1><<<dim3(49, 4, 2), 256, 0, stream>>>(
            z, z, 256, fw, bw, fb, bb, xc1, xc2, 256, NROWS, 256, 256);
        /* dbc = xc @ dbc_w^T (160 wide) */
        gemm_kernel<0><<<dim3(49, 3, 2), 256, 0, stream>>>(
            xc1, xc2, 256, dw, dw, nullptr, nullptr, dbc1, dbc2, 160,
            NROWS, 160, 256);
        /* delta = softplus(dbc[:, :32] @ dt_w^T + dt_b) */
        gemm_kernel<1><<<dim3(49, 4, 2), 256, 0, stream>>>(
            dbc1, dbc2, 160, tw, tw, tb, tb, delta1, delta2, 256,
            NROWS, 256, 32);
        /* selective scan */
        ssm_kernel<<<dim3(1024, 2), 256, 0, stream>>>(
            xc1, xc2, dbc1, dbc2, delta1, delta2, y1, y2, Al, Dl);
        /* gate + residual + LN for next layer */
        combine_ln_kernel<<<NROWS / 4, 256, 0, stream>>>(
            y1, y2, z, t_buf, xn, ng, nb);
    }

    head_kernel<<<BATCH, 256, 0, stream>>>(t_buf, head_g, head_b, head_w,
                                           head_bias, out);
}

// Round 10
// 2071.461 us; speedup vs baseline: 1.2572x; 1.2572x over previous
//
#include <hip/hip_runtime.h>
#include <hip/hip_bf16.h>

#define DIMD 256
#define SEQ 196
#define BATCH 16
#define NST 64
#define NROWS (BATCH * SEQ) /* 3136 */

__device__ __forceinline__ float softplus_f(float x) {
    return fmaxf(x, 0.f) + log1pf(expf(-fabsf(x)));
}

/* ---------------- patch gather: x (B,3,224,224) -> xp (B,196,768) ---------------- */
__global__ __launch_bounds__(256) void gather_kernel(const float* __restrict__ x,
                                                     float* __restrict__ xp) {
    int i = blockIdx.x * 256 + threadIdx.x;
    if (i >= BATCH * SEQ * 768) return;
    int j = i % 768;
    int s = (i / 768) % SEQ;
    int b = i / (768 * SEQ);
    int c = j % 3;
    int p2 = (j / 3) % 16;
    int p1 = j / 48;
    int hp = s / 14, wp = s % 14;
    int hh = hp * 16 + p1, ww = wp * 16 + p2;
    xp[i] = x[((long)(b * 3 + c) * 224 + hh) * 224 + ww];
}

/* ---------------- generic f32 GEMM: C[m,n] = act(sum_k A[m,k]*W[n,k] + bias[n]) ----
   blockIdx.z selects operand set (for fwd/bwd direction pairs).
   BM=BN=64, BK=32, 256 threads, thread computes 4x4. M must be multiple of 64. */
#define BM 64
#define BN 64
#define BK 32

template <int ACT> /* 0 = none, 1 = softplus */
__global__ __launch_bounds__(256) void gemm_kernel(
    const float* __restrict__ A0, const float* __restrict__ A1, int lda,
    const float* __restrict__ W0, const float* __restrict__ W1,
    const float* __restrict__ b0, const float* __restrict__ b1,
    float* __restrict__ C0, float* __restrict__ C1, int ldc,
    int M, int N, int K) {
    const float* A = blockIdx.z ? A1 : A0;
    const float* W = blockIdx.z ? W1 : W0;
    const float* bias = blockIdx.z ? b1 : b0;
    float* C = blockIdx.z ? C1 : C0;

    __shared__ float As[BK][BM];
    __shared__ float Ws[BK][BN];

    const int tid = threadIdx.x;
    const int m0 = blockIdx.x * BM;
    const int n0 = blockIdx.y * BN;
    const int tx = tid & 15, ty = tid >> 4;
    const int lrow = tid >> 3;        /* 0..31 */
    const int lcol = (tid & 7) * 4;   /* 0..28 */

    float acc[4][4] = {};

    for (int k0 = 0; k0 < K; k0 += BK) {
#pragma unroll
        for (int h = 0; h < 2; ++h) {
            int m = lrow + h * 32;
            float4 v = *reinterpret_cast<const float4*>(&A[(long)(m0 + m) * lda + k0 + lcol]);
            As[lcol + 0][m] = v.x; As[lcol + 1][m] = v.y;
            As[lcol + 2][m] = v.z; As[lcol + 3][m] = v.w;
        }
#pragma unroll
        for (int h = 0; h < 2; ++h) {
            int n = lrow + h * 32;
            float4 v = make_float4(0.f, 0.f, 0.f, 0.f);
            if (n0 + n < N)
                v = *reinterpret_cast<const float4*>(&W[(long)(n0 + n) * K + k0 + lcol]);
            Ws[lcol + 0][n] = v.x; Ws[lcol + 1][n] = v.y;
            Ws[lcol + 2][n] = v.z; Ws[lcol + 3][n] = v.w;
        }
        __syncthreads();
#pragma unroll
        for (int k = 0; k < BK; ++k) {
            float4 a = *reinterpret_cast<const float4*>(&As[k][ty * 4]);
            float4 w = *reinterpret_cast<const float4*>(&Ws[k][tx * 4]);
            float av[4] = {a.x, a.y, a.z, a.w};
            float wv[4] = {w.x, w.y, w.z, w.w};
#pragma unroll
            for (int i = 0; i < 4; ++i)
#pragma unroll
                for (int j = 0; j < 4; ++j)
                    acc[i][j] = fmaf(av[i], wv[j], acc[i][j]);
        }
        __syncthreads();
    }

    float bv[4];
#pragma unroll
    for (int j = 0; j < 4; ++j) {
        int n = n0 + tx * 4 + j;
        bv[j] = (b0 != nullptr && n < N) ? bias[n] : 0.f;
    }
#pragma unroll
    for (int i = 0; i < 4; ++i) {
        int m = m0 + ty * 4 + i;
        int n = n0 + tx * 4;
        if (n + 3 < N) {
            float4 o;
            float v0 = acc[i][0] + bv[0], v1 = acc[i][1] + bv[1];
            float v2 = acc[i][2] + bv[2], v3 = acc[i][3] + bv[3];
            if (ACT == 1) { v0 = softplus_f(v0); v1 = softplus_f(v1);
                            v2 = softplus_f(v2); v3 = softplus_f(v3); }
            o.x = v0; o.y = v1; o.z = v2; o.w = v3;
            *reinterpret_cast<float4*>(&C[(long)m * ldc + n]) = o;
        } else {
#pragma unroll
            for (int j = 0; j < 4; ++j)
                if (n + j < N) {
                    float v = acc[i][j] + bv[j];
                    if (ACT == 1) v = softplus_f(v);
                    C[(long)m * ldc + n + j] = v;
                }
        }
    }
}

/* ---------------- LayerNorm over last dim (256), one wave per row ---------------- */
__global__ __launch_bounds__(256) void ln_kernel(const float* __restrict__ in,
                                                 float* __restrict__ out,
                                                 const float* __restrict__ g,
                                                 const float* __restrict__ b) {
    int wid = blockIdx.x * 4 + (threadIdx.x >> 6);
    int lane = threadIdx.x & 63;
    const float* row = in + (long)wid * DIMD;
    float4 v = *reinterpret_cast<const float4*>(&row[lane * 4]);
    float s = v.x + v.y + v.z + v.w;
    float q = v.x * v.x + v.y * v.y + v.z * v.z + v.w * v.w;
#pragma unroll
    for (int m = 32; m >= 1; m >>= 1) {
        s += __shfl_xor(s, m, 64);
        q += __shfl_xor(q, m, 64);
    }
    float mean = s * (1.f / 256.f);
    float var = q * (1.f / 256.f) - mean * mean;
    float rstd = rsqrtf(var + 1e-5f);
    float4 gv = *reinterpret_cast<const float4*>(&g[lane * 4]);
    float4 bv = *reinterpret_cast<const float4*>(&b[lane * 4]);
    float4 o;
    o.x = (v.x - mean) * rstd * gv.x + bv.x;
    o.y = (v.y - mean) * rstd * gv.y + bv.y;
    o.z = (v.z - mean) * rstd * gv.z + bv.z;
    o.w = (v.w - mean) * rstd * gv.w + bv.w;
    *reinterpret_cast<float4*>(&out[(long)wid * DIMD + lane * 4]) = o;
}

/* ---------------- selective scan: wave = (b,d), lane = state n ----------------
   Packed 4-step reduce: the per-step 6-op shuffle tree was DS-pipe-bound
   (rocprof r9: 125us/dispatch, VALUBusy 45%, HBM 7.7%). Batch 4 sequence
   steps, reduce the four 64-lane sums with 12 DS ops instead of 24:
   per-value xor{32,16} -> one value per 16-lane group -> shared xor{8,4,2,1}. */
__global__ __launch_bounds__(256) void ssm_kernel(
    const float* __restrict__ xcA, const float* __restrict__ xcB,
    const float* __restrict__ dbcA, const float* __restrict__ dbcB,
    const float* __restrict__ deA, const float* __restrict__ deB,
    float* __restrict__ yA, float* __restrict__ yB,
    const float* __restrict__ A_log, const float* __restrict__ Dp) {
    const int dir = blockIdx.y;
    const float* xc = dir ? xcB : xcA;
    const float* dbc = dir ? dbcB : dbcA;
    const float* de = dir ? deB : deA;
    float* y = dir ? yB : yA;

    int w = blockIdx.x * 4 + (threadIdx.x >> 6); /* 0..4095 */
    int lane = threadIdx.x & 63;
    int b = w >> 8, d = w & 255;

    /* A2 = -exp(A_log) * log2(e) so that exp(delta*A) = exp2(delta*A2) */
    float A2 = -expf(A_log[d * NST + lane]) * 1.44269504088896341f;
    float Dv = Dp[d];

    const float* deRow = de + (long)b * SEQ * DIMD + d;
    const float* xcRow = xc + (long)b * SEQ * DIMD + d;
    const float* dbcRow = dbc + (long)b * SEQ * 160;
    float* yRow = y + (long)b * SEQ * DIMD + d;

    const int q = lane >> 4;          /* 0..3: which of the 4 batched steps */
    const bool storer = (lane & 15) == 0;

    float h = 0.f;
    for (int s0 = 0; s0 < SEQ; s0 += 4) {   /* SEQ = 196 = 4*49, no tail */
        float v0, v1, v2, v3, x0, x1, x2, x3;
        {
            float du = deRow[(long)(s0 + 0) * DIMD];
            float xu = xcRow[(long)(s0 + 0) * DIMD];
            float Bn = dbcRow[(long)(s0 + 0) * 160 + 32 + lane];
            float Cn = dbcRow[(long)(s0 + 0) * 160 + 96 + lane];
            h = fmaf(exp2f(du * A2), h, (du * xu) * Bn);
            v0 = h * Cn; x0 = xu;
        }
        {
            float du = deRow[(long)(s0 + 1) * DIMD];
            float xu = xcRow[(long)(s0 + 1) * DIMD];
            float Bn = dbcRow[(long)(s0 + 1) * 160 + 32 + lane];
            float Cn = dbcRow[(long)(s0 + 1) * 160 + 96 + lane];
            h = fmaf(exp2f(du * A2), h, (du * xu) * Bn);
            v1 = h * Cn; x1 = xu;
        }
        {
            float du = deRow[(long)(s0 + 2) * DIMD];
            float xu = xcRow[(long)(s0 + 2) * DIMD];
            float Bn = dbcRow[(long)(s0 + 2) * 160 + 32 + lane];
            float Cn = dbcRow[(long)(s0 + 2) * 160 + 96 + lane];
            h = fmaf(exp2f(du * A2), h, (du * xu) * Bn);
            v2 = h * Cn; x2 = xu;
        }
        {
            float du = deRow[(long)(s0 + 3) * DIMD];
            float xu = xcRow[(long)(s0 + 3) * DIMD];
            float Bn = dbcRow[(long)(s0 + 3) * 160 + 32 + lane];
            float Cn = dbcRow[(long)(s0 + 3) * 160 + 96 + lane];
            h = fmaf(exp2f(du * A2), h, (du * xu) * Bn);
            v3 = h * Cn; x3 = xu;
        }
        /* packed 4-way reduce: 12 DS ops for 4 sums (was 24) */
        v0 += __shfl_xor(v0, 32, 64); v1 += __shfl_xor(v1, 32, 64);
        v2 += __shfl_xor(v2, 32, 64); v3 += __shfl_xor(v3, 32, 64);
        v0 += __shfl_xor(v0, 16, 64); v1 += __shfl_xor(v1, 16, 64);
        v2 += __shfl_xor(v2, 16, 64); v3 += __shfl_xor(v3, 16, 64);
        /* each lane now holds the partial sum of its residue class (lane&15);
           select step (lane>>4)'s partial into r */
        float r  = (q == 0) ? v0 : (q == 1) ? v1 : (q == 2) ? v2 : v3;
        r += __shfl_xor(r, 8, 64);
        r += __shfl_xor(r, 4, 64);
        r += __shfl_xor(r, 2, 64);
        r += __shfl_xor(r, 1, 64);
        /* lane group q holds the full sum for step s0+q; lane q*16 stores */
        if (storer) {
            float xq = (q == 0) ? x0 : (q == 1) ? x1 : (q == 2) ? x2 : x3;
            yRow[(long)(s0 + q) * DIMD] = r + Dv * xq;
        }
    }
}

/* ---------------- combine + LN for next layer, one wave per row ---------------- */
__global__ __launch_bounds__(256) void combine_ln_kernel(
    const float* __restrict__ y1, const float* __restrict__ y2,
    const float* __restrict__ z, float* __restrict__ t,
    float* __restrict__ xn, const float* __restrict__ g,
    const float* __restrict__ b) {
    int wid = blockIdx.x * 4 + (threadIdx.x >> 6);
    int lane = threadIdx.x & 63;
    long base = (long)wid * DIMD + lane * 4;
    float4 a = *reinterpret_cast<const float4*>(&y1[base]);
    float4 c = *reinterpret_cast<const float4*>(&y2[base]);
    float4 zz = *reinterpret_cast<const float4*>(&z[base]);
    float4 tt = *reinterpret_cast<const float4*>(&t[base]);
    float4 tn;
    {
        float zs;
        zs = zz.x / (1.f + expf(-zz.x)); tn.x = (a.x + c.x) * zs + tt.x;
        zs = zz.y / (1.f + expf(-zz.y)); tn.y = (a.y + c.y) * zs + tt.y;
        zs = zz.z / (1.f + expf(-zz.z)); tn.z = (a.z + c.z) * zs + tt.z;
        zs = zz.w / (1.f + expf(-zz.w)); tn.w = (a.w + c.w) * zs + tt.w;
    }
    *reinterpret_cast<float4*>(&t[base]) = tn;
    float s = tn.x + tn.y + tn.z + tn.w;
    float q = tn.x * tn.x + tn.y * tn.y + tn.z * tn.z + tn.w * tn.w;
#pragma unroll
    for (int m = 32; m >= 1; m >>= 1) {
        s += __shfl_xor(s, m, 64);
        q += __shfl_xor(q, m, 64);
    }
    float mean = s * (1.f / 256.f);
    float var = q * (1.f / 256.f) - mean * mean;
    float rstd = rsqrtf(var + 1e-5f);
    float4 gv = *reinterpret_cast<const float4*>(&g[lane * 4]);
    float4 bv = *reinterpret_cast<const float4*>(&b[lane * 4]);
    float4 o;
    o.x = (tn.x - mean) * rstd * gv.x + bv.x;
    o.y = (tn.y - mean) * rstd * gv.y + bv.y;
    o.z = (tn.z - mean) * rstd * gv.z + bv.z;
    o.w = (tn.w - mean) * rstd * gv.w + bv.w;
    *reinterpret_cast<float4*>(&xn[base]) = o;
}

/* ---------------- head: pool + LN + linear(1000) + softmax, block per batch ----- */
__global__ __launch_bounds__(256) void head_kernel(
    const float* __restrict__ t, const float* __restrict__ hg,
    const float* __restrict__ hb, const float* __restrict__ hw,
    const float* __restrict__ hbias, float* __restrict__ out) {
    __shared__ float xh[DIMD];
    __shared__ float red[8];
    __shared__ float logits[1000];
    int b = blockIdx.x, tid = threadIdx.x;
    int wv = tid >> 6, ln = tid & 63;

    /* mean pool over S */
    float s = 0.f;
    const float* tb = t + (long)b * SEQ * DIMD;
    for (int si = 0; si < SEQ; ++si) s += tb[(long)si * DIMD + tid];
    s *= (1.f / (float)SEQ);

    /* LN over 256 across threads */
    float sum = s, sq = s * s;
#pragma unroll
    for (int m = 32; m >= 1; m >>= 1) {
        sum += __shfl_xor(sum, m, 64);
        sq += __shfl_xor(sq, m, 64);
    }
    if (ln == 0) { red[wv] = sum; red[4 + wv] = sq; }
    __syncthreads();
    float S = red[0] + red[1] + red[2] + red[3];
    float Q = red[4] + red[5] + red[6] + red[7];
    float mean = S * (1.f / 256.f);
    float var = Q * (1.f / 256.f) - mean * mean;
    float rstd = rsqrtf(var + 1e-5f);
    xh[tid] = (s - mean) * rstd * hg[tid] + hb[tid];
    __syncthreads();

    /* logits */
    for (int c = tid; c < 1000; c += 256) {
        float acc = hbias[c];
        const float* wr = hw + (long)c * DIMD;
        for (int k = 0; k < DIMD; k += 4) {
            float4 w4 = *reinterpret_cast<const float4*>(&wr[k]);
            acc += xh[k] * w4.x + xh[k + 1] * w4.y + xh[k + 2] * w4.z + xh[k + 3] * w4.w;
        }
        logits[c] = acc;
    }
    __syncthreads();

    /* softmax */
    float mx = -1e30f;
    for (int c = tid; c < 1000; c += 256) mx = fmaxf(mx, logits[c]);
#pragma unroll
    for (int m = 32; m >= 1; m >>= 1) mx = fmaxf(mx, __shfl_xor(mx, m, 64));
    if (ln == 0) red[wv] = mx;
    __syncthreads();
    mx = fmaxf(fmaxf(red[0], red[1]), fmaxf(red[2], red[3]));
    float se = 0.f;
    for (int c = tid; c < 1000; c += 256) {
        float e = expf(logits[c] - mx);
        logits[c] = e;
        se += e;
    }
#pragma unroll
    for (int m = 32; m >= 1; m >>= 1) se += __shfl_xor(se, m, 64);
    __syncthreads();
    if (ln == 0) red[4 + wv] = se;
    __syncthreads();
    se = red[4] + red[5] + red[6] + red[7];
    float inv = 1.f / se;
    for (int c = tid; c < 1000; c += 256)
        out[b * 1000 + c] = logits[c] * inv;
}

/* ============================== host launcher ============================== */
extern "C" void kernel_launch(void* const* d_in, const int* in_sizes, int n_in,
                              void* d_out, int out_size, void* d_ws, size_t ws_size,
                              hipStream_t stream) {
    const float* x       = (const float*)d_in[0];
    const float* patch_w = (const float*)d_in[1];
    const float* patch_b = (const float*)d_in[2];
    const float* norm_g  = (const float*)d_in[3];
    const float* norm_b  = (const float*)d_in[4];
    const float* proj_w  = (const float*)d_in[5];
    const float* proj_b  = (const float*)d_in[6];
    const float* fconv_w = (const float*)d_in[7];
    const float* fconv_b = (const float*)d_in[8];
    const float* bconv_w = (const float*)d_in[9];
    const float* bconv_b = (const float*)d_in[10];
    const float* dbc_w   = (const float*)d_in[11];
    const float* dt_w    = (const float*)d_in[12];
    const float* dt_b    = (const float*)d_in[13];
    const float* A_log   = (const float*)d_in[14];
    const float* Dp      = (const float*)d_in[15];
    const float* head_g  = (const float*)d_in[16];
    const float* head_b  = (const float*)d_in[17];
    const float* head_w  = (const float*)d_in[18];
    const float* head_bias = (const float*)d_in[19];
    float* out = (float*)d_out; /* reference output dtype is FLOAT32 (softmax of f32) */

    float* ws = (float*)d_ws;
    const long NTOK = (long)NROWS * DIMD; /* 802816 */
    float* t_buf  = ws;
    float* xn     = ws + NTOK;
    float* z      = ws + 2 * NTOK;
    float* delta1 = ws + 3 * NTOK;
    float* delta2 = ws + 4 * NTOK;
    float* y1     = ws + 5 * NTOK;
    float* y2     = ws + 6 * NTOK;
    float* dbc2   = ws + 7 * NTOK; /* 3136*160 = 501760 */
    float* xp     = ws + 7 * NTOK + 501760;
    float* xc1    = xp;            /* reuse xp region after patch embed */
    float* xc2    = xp + NTOK;
    float* dbc1   = xp + 2 * NTOK; /* 501760, fits inside xp (2408448) */

    /* patch embed */
    gather_kernel<<<(BATCH * SEQ * 768 + 255) / 256, 256, 0, stream>>>(x, xp);
    gemm_kernel<0><<<dim3(49, 4, 1), 256, 0, stream>>>(
        xp, xp, 768, patch_w, patch_w, patch_b, patch_b, t_buf, t_buf, 256,
        NROWS, 256, 768);

    ln_kernel<<<NROWS / 4, 256, 0, stream>>>(t_buf, xn, norm_g, norm_b);

    for (int L = 0; L < 12; ++L) {
        const float* pw  = proj_w + (long)L * 256 * 256;
        const float* pb  = proj_b + (long)L * 256;
        const float* fw  = fconv_w + (long)L * 256 * 256;
        const float* fb  = fconv_b + (long)L * 256;
        const float* bw  = bconv_w + (long)L * 256 * 256;
        const float* bb  = bconv_b + (long)L * 256;
        const float* dw  = dbc_w + (long)L * 160 * 256;
        const float* tw  = dt_w + (long)L * 256 * 32;
        const float* tb  = dt_b + (long)L * 256;
        const float* Al  = A_log + (long)L * 256 * 64;
        const float* Dl  = Dp + (long)L * 256;
        int Ln = (L + 1) % 12;
        const float* ng = norm_g + (long)Ln * 256;
        const float* nb = norm_b + (long)Ln * 256;

        /* z = xn @ proj^T + pb */
        gemm_kernel<0><<<dim3(49, 4, 1), 256, 0, stream>>>(
            xn, xn, 256, pw, pw, pb, pb, z, z, 256, NROWS, 256, 256);
        /* xc = softplus(z @ conv^T + cb), both directions */
        gemm_kernel<1><<<dim3(49, 4, 2), 256, 0, stream>>>(
            z, z, 256, fw, bw, fb, bb, xc1, xc2, 256, NROWS, 256, 256);
        /* dbc = xc @ dbc_w^T (160 wide) */
        gemm_kernel<0><<<dim3(49, 3, 2), 256, 0, stream>>>(
            xc1, xc2, 256, dw, dw, nullptr, nullptr, dbc1, dbc2, 160,
            NROWS, 160, 256);
        /* delta = softplus(dbc[:, :32] @ dt_w^T + dt_b) */
        gemm_kernel<1><<<dim3(49, 4, 2), 256, 0, stream>>>(
            dbc1, dbc2, 160, tw, tw, tb, tb, delta1, delta2, 256,
            NROWS, 256, 32);
        /* selective scan */
        ssm_kernel<<<dim3(1024, 2), 256, 0, stream>>>(
            xc1, xc2, dbc1, dbc2, delta1, delta2, y1, y2, Al, Dl);
        /* gate + residual + LN for next layer */
        combine_ln_kernel<<<NROWS / 4, 256, 0, stream>>>(
            y1, y2, z, t_buf, xn, ng, nb);
    }

    head_kernel<<<BATCH, 256, 0, stream>>>(t_buf, head_g, head_b, head_w,
                                           head_bias, out);
}

// Round 14
// 1557.676 us; speedup vs baseline: 1.6719x; 1.3298x over previous
//
#include <hip/hip_runtime.h>
#include <hip/hip_bf16.h>

#define DIMD 256
#define SEQ 196
#define BATCH 16
#define NST 64
#define NROWS (BATCH * SEQ) /* 3136 */

typedef __attribute__((ext_vector_type(8))) short short8v; /* 8 bf16 (4 VGPRs) */
typedef __attribute__((ext_vector_type(4))) float f32x4;

__device__ __forceinline__ float softplus_f(float x) {
    return fmaxf(x, 0.f) + log1pf(expf(-fabsf(x)));
}

/* ---------------- f32 -> bf16 conversion (weights, once per call) ---------------- */
__global__ __launch_bounds__(256) void cvt_bf16_kernel(const float* __restrict__ in,
                                                       __hip_bfloat16* __restrict__ out,
                                                       int n) {
    for (int i = blockIdx.x * 256 + threadIdx.x; i < n; i += gridDim.x * 256)
        out[i] = __float2bfloat16(in[i]);
}

/* ---------------- patch gather: x (B,3,224,224) -> xp (B,196,768) ---------------- */
__global__ __launch_bounds__(256) void gather_kernel(const float* __restrict__ x,
                                                     float* __restrict__ xp) {
    int i = blockIdx.x * 256 + threadIdx.x;
    if (i >= BATCH * SEQ * 768) return;
    int j = i % 768;
    int s = (i / 768) % SEQ;
    int b = i / (768 * SEQ);
    int c = j % 3;
    int p2 = (j / 3) % 16;
    int p1 = j / 48;
    int hp = s / 14, wp = s % 14;
    int hh = hp * 16 + p1, ww = wp * 16 + p2;
    xp[i] = x[((long)(b * 3 + c) * 224 + hh) * 224 + ww];
}

/* ---------------- f32 GEMM (kept for patch embed K=768 and delta K=32) ---------- */
#define BM 64
#define BN 64
#define BK 32

template <int ACT>
__global__ __launch_bounds__(256) void gemm_kernel(
    const float* __restrict__ A0, const float* __restrict__ A1, int lda,
    const float* __restrict__ W0, const float* __restrict__ W1,
    const float* __restrict__ b0, const float* __restrict__ b1,
    float* __restrict__ C0, float* __restrict__ C1, int ldc,
    int M, int N, int K) {
    const float* A = blockIdx.z ? A1 : A0;
    const float* W = blockIdx.z ? W1 : W0;
    const float* bias = blockIdx.z ? b1 : b0;
    float* C = blockIdx.z ? C1 : C0;

    __shared__ float As[BK][BM];
    __shared__ float Ws[BK][BN];

    const int tid = threadIdx.x;
    const int m0 = blockIdx.x * BM;
    const int n0 = blockIdx.y * BN;
    const int tx = tid & 15, ty = tid >> 4;
    const int lrow = tid >> 3;
    const int lcol = (tid & 7) * 4;

    float acc[4][4] = {};

    for (int k0 = 0; k0 < K; k0 += BK) {
#pragma unroll
        for (int h = 0; h < 2; ++h) {
            int m = lrow + h * 32;
            float4 v = *reinterpret_cast<const float4*>(&A[(long)(m0 + m) * lda + k0 + lcol]);
            As[lcol + 0][m] = v.x; As[lcol + 1][m] = v.y;
            As[lcol + 2][m] = v.z; As[lcol + 3][m] = v.w;
        }
#pragma unroll
        for (int h = 0; h < 2; ++h) {
            int n = lrow + h * 32;
            float4 v = make_float4(0.f, 0.f, 0.f, 0.f);
            if (n0 + n < N)
                v = *reinterpret_cast<const float4*>(&W[(long)(n0 + n) * K + k0 + lcol]);
            Ws[lcol + 0][n] = v.x; Ws[lcol + 1][n] = v.y;
            Ws[lcol + 2][n] = v.z; Ws[lcol + 3][n] = v.w;
        }
        __syncthreads();
#pragma unroll
        for (int k = 0; k < BK; ++k) {
            float4 a = *reinterpret_cast<const float4*>(&As[k][ty * 4]);
            float4 w = *reinterpret_cast<const float4*>(&Ws[k][tx * 4]);
            float av[4] = {a.x, a.y, a.z, a.w};
            float wv[4] = {w.x, w.y, w.z, w.w};
#pragma unroll
            for (int i = 0; i < 4; ++i)
#pragma unroll
                for (int j = 0; j < 4; ++j)
                    acc[i][j] = fmaf(av[i], wv[j], acc[i][j]);
        }
        __syncthreads();
    }

    float bv[4];
#pragma unroll
    for (int j = 0; j < 4; ++j) {
        int n = n0 + tx * 4 + j;
        bv[j] = (b0 != nullptr && n < N) ? bias[n] : 0.f;
    }
#pragma unroll
    for (int i = 0; i < 4; ++i) {
        int m = m0 + ty * 4 + i;
        int n = n0 + tx * 4;
        if (n + 3 < N) {
            float4 o;
            float v0 = acc[i][0] + bv[0], v1 = acc[i][1] + bv[1];
            float v2 = acc[i][2] + bv[2], v3 = acc[i][3] + bv[3];
            if (ACT == 1) { v0 = softplus_f(v0); v1 = softplus_f(v1);
                            v2 = softplus_f(v2); v3 = softplus_f(v3); }
            o.x = v0; o.y = v1; o.z = v2; o.w = v3;
            *reinterpret_cast<float4*>(&C[(long)m * ldc + n]) = o;
        } else {
#pragma unroll
            for (int j = 0; j < 4; ++j)
                if (n + j < N) {
                    float v = acc[i][j] + bv[j];
                    if (ACT == 1) v = softplus_f(v);
                    C[(long)m * ldc + n + j] = v;
                }
        }
    }
}

/* ---------------- bf16 MFMA GEMM: C = act(A @ W^T + bias), K=256 ----------------
   64x64 tile, 4 waves, wave computes 64 rows x 16 cols via 4x mfma_f32_16x16x32.
   A,W bf16 row-major K-contiguous: a/b fragments load identically (guide §3 m92).
   C/D layout: col=lane&15, row=(lane>>4)*4+reg (m89-verified).
   LDS rows padded to 40 shorts (80B): bank step 20 -> ~2-way aliasing = free (m136). */
template <int ACT, int WB16> /* ACT: 0 none, 1 softplus; WB16: also write bf16 copy */
__global__ __launch_bounds__(256) void mfma_gemm(
    const __hip_bfloat16* __restrict__ A0, const __hip_bfloat16* __restrict__ A1,
    const __hip_bfloat16* __restrict__ W0, const __hip_bfloat16* __restrict__ W1,
    const float* __restrict__ b0, const float* __restrict__ b1,
    float* __restrict__ C0, float* __restrict__ C1,
    __hip_bfloat16* __restrict__ Cb0, __hip_bfloat16* __restrict__ Cb1,
    int N, int ldc) {
    const __hip_bfloat16* A = blockIdx.z ? A1 : A0;
    const __hip_bfloat16* W = blockIdx.z ? W1 : W0;
    const float* bias = blockIdx.z ? b1 : b0;
    float* C = blockIdx.z ? C1 : C0;
    __hip_bfloat16* Cb = blockIdx.z ? Cb1 : Cb0;

    __shared__ short As[64 * 40];
    __shared__ short Ws[64 * 40];

    const int tid = threadIdx.x;
    const int m0 = blockIdx.x * 64;
    const int n0 = blockIdx.y * 64;
    const int srow = tid >> 2;       /* 0..63: staged row */
    const int skq = tid & 3;         /* 0..3: 8-elem k-chunk */
    const int lane = tid & 63;
    const int wid = tid >> 6;        /* wave 0..3 -> 16-col strip */
    const int l15 = lane & 15, lg = lane >> 4;

    f32x4 acc[4] = {{0.f, 0.f, 0.f, 0.f}, {0.f, 0.f, 0.f, 0.f},
                    {0.f, 0.f, 0.f, 0.f}, {0.f, 0.f, 0.f, 0.f}};

    for (int k0 = 0; k0 < DIMD; k0 += 32) {
        /* stage: each thread one 16B chunk of A-tile and W-tile */
        *reinterpret_cast<short8v*>(&As[srow * 40 + skq * 8]) =
            *reinterpret_cast<const short8v*>(
                reinterpret_cast<const short*>(A) + (long)(m0 + srow) * DIMD + k0 + skq * 8);
        short8v wv8 = {0, 0, 0, 0, 0, 0, 0, 0};
        if (n0 + srow < N)
            wv8 = *reinterpret_cast<const short8v*>(
                reinterpret_cast<const short*>(W) + (long)(n0 + srow) * DIMD + k0 + skq * 8);
        *reinterpret_cast<short8v*>(&Ws[srow * 40 + skq * 8]) = wv8;
        __syncthreads();

        short8v bfr = *reinterpret_cast<const short8v*>(&Ws[(wid * 16 + l15) * 40 + lg * 8]);
#pragma unroll
        for (int i = 0; i < 4; ++i) {
            short8v afr = *reinterpret_cast<const short8v*>(&As[(i * 16 + l15) * 40 + lg * 8]);
            acc[i] = __builtin_amdgcn_mfma_f32_16x16x32_bf16(afr, bfr, acc[i], 0, 0, 0);
        }
        __syncthreads();
    }

    const int col = n0 + wid * 16 + l15;
    if (col < N) {
        float bv = (b0 != nullptr) ? bias[col] : 0.f;
#pragma unroll
        for (int i = 0; i < 4; ++i) {
#pragma unroll
            for (int r = 0; r < 4; ++r) {
                int row = m0 + i * 16 + lg * 4 + r;
                float v = acc[i][r] + bv;
                if (ACT == 1) v = softplus_f(v);
                C[(long)row * ldc + col] = v;
                if (WB16) Cb[(long)row * ldc + col] = __float2bfloat16(v);
            }
        }
    }
}

/* ---------------- LayerNorm over last dim (256), one wave per row ---------------- */
__global__ __launch_bounds__(256) void ln_kernel(const float* __restrict__ in,
                                                 float* __restrict__ out,
                                                 __hip_bfloat16* __restrict__ out16,
                                                 const float* __restrict__ g,
                                                 const float* __restrict__ b) {
    int wid = blockIdx.x * 4 + (threadIdx.x >> 6);
    int lane = threadIdx.x & 63;
    const float* row = in + (long)wid * DIMD;
    float4 v = *reinterpret_cast<const float4*>(&row[lane * 4]);
    float s = v.x + v.y + v.z + v.w;
    float q = v.x * v.x + v.y * v.y + v.z * v.z + v.w * v.w;
#pragma unroll
    for (int m = 32; m >= 1; m >>= 1) {
        s += __shfl_xor(s, m, 64);
        q += __shfl_xor(q, m, 64);
    }
    float mean = s * (1.f / 256.f);
    float var = q * (1.f / 256.f) - mean * mean;
    float rstd = rsqrtf(var + 1e-5f);
    float4 gv = *reinterpret_cast<const float4*>(&g[lane * 4]);
    float4 bv = *reinterpret_cast<const float4*>(&b[lane * 4]);
    float4 o;
    o.x = (v.x - mean) * rstd * gv.x + bv.x;
    o.y = (v.y - mean) * rstd * gv.y + bv.y;
    o.z = (v.z - mean) * rstd * gv.z + bv.z;
    o.w = (v.w - mean) * rstd * gv.w + bv.w;
    long base = (long)wid * DIMD + lane * 4;
    *reinterpret_cast<float4*>(&out[base]) = o;
    out16[base + 0] = __float2bfloat16(o.x);
    out16[base + 1] = __float2bfloat16(o.y);
    out16[base + 2] = __float2bfloat16(o.z);
    out16[base + 3] = __float2bfloat16(o.w);
}

/* ---------------- selective scan: wave = (b,d), lane = state n ----------------
   Packed 4-step reduce (r10: 78.5us/dispatch, DS ops 3/step). */
__global__ __launch_bounds__(256) void ssm_kernel(
    const float* __restrict__ xcA, const float* __restrict__ xcB,
    const float* __restrict__ dbcA, const float* __restrict__ dbcB,
    const float* __restrict__ deA, const float* __restrict__ deB,
    float* __restrict__ yA, float* __restrict__ yB,
    const float* __restrict__ A_log, const float* __restrict__ Dp) {
    const int dir = blockIdx.y;
    const float* xc = dir ? xcB : xcA;
    const float* dbc = dir ? dbcB : dbcA;
    const float* de = dir ? deB : deA;
    float* y = dir ? yB : yA;

    int w = blockIdx.x * 4 + (threadIdx.x >> 6);
    int lane = threadIdx.x & 63;
    int b = w >> 8, d = w & 255;

    float A2 = -expf(A_log[d * NST + lane]) * 1.44269504088896341f;
    float Dv = Dp[d];

    const float* deRow = de + (long)b * SEQ * DIMD + d;
    const float* xcRow = xc + (long)b * SEQ * DIMD + d;
    const float* dbcRow = dbc + (long)b * SEQ * 160;
    float* yRow = y + (long)b * SEQ * DIMD + d;

    const int q = lane >> 4;
    const bool storer = (lane & 15) == 0;

    float h = 0.f;
    for (int s0 = 0; s0 < SEQ; s0 += 4) {
        float v0, v1, v2, v3, x0, x1, x2, x3;
        {
            float du = deRow[(long)(s0 + 0) * DIMD];
            float xu = xcRow[(long)(s0 + 0) * DIMD];
            float Bn = dbcRow[(long)(s0 + 0) * 160 + 32 + lane];
            float Cn = dbcRow[(long)(s0 + 0) * 160 + 96 + lane];
            h = fmaf(exp2f(du * A2), h, (du * xu) * Bn);
            v0 = h * Cn; x0 = xu;
        }
        {
            float du = deRow[(long)(s0 + 1) * DIMD];
            float xu = xcRow[(long)(s0 + 1) * DIMD];
            float Bn = dbcRow[(long)(s0 + 1) * 160 + 32 + lane];
            float Cn = dbcRow[(long)(s0 + 1) * 160 + 96 + lane];
            h = fmaf(exp2f(du * A2), h, (du * xu) * Bn);
            v1 = h * Cn; x1 = xu;
        }
        {
            float du = deRow[(long)(s0 + 2) * DIMD];
            float xu = xcRow[(long)(s0 + 2) * DIMD];
            float Bn = dbcRow[(long)(s0 + 2) * 160 + 32 + lane];
            float Cn = dbcRow[(long)(s0 + 2) * 160 + 96 + lane];
            h = fmaf(exp2f(du * A2), h, (du * xu) * Bn);
            v2 = h * Cn; x2 = xu;
        }
        {
            float du = deRow[(long)(s0 + 3) * DIMD];
            float xu = xcRow[(long)(s0 + 3) * DIMD];
            float Bn = dbcRow[(long)(s0 + 3) * 160 + 32 + lane];
            float Cn = dbcRow[(long)(s0 + 3) * 160 + 96 + lane];
            h = fmaf(exp2f(du * A2), h, (du * xu) * Bn);
            v3 = h * Cn; x3 = xu;
        }
        v0 += __shfl_xor(v0, 32, 64); v1 += __shfl_xor(v1, 32, 64);
        v2 += __shfl_xor(v2, 32, 64); v3 += __shfl_xor(v3, 32, 64);
        v0 += __shfl_xor(v0, 16, 64); v1 += __shfl_xor(v1, 16, 64);
        v2 += __shfl_xor(v2, 16, 64); v3 += __shfl_xor(v3, 16, 64);
        float r = (q == 0) ? v0 : (q == 1) ? v1 : (q == 2) ? v2 : v3;
        r += __shfl_xor(r, 8, 64);
        r += __shfl_xor(r, 4, 64);
        r += __shfl_xor(r, 2, 64);
        r += __shfl_xor(r, 1, 64);
        if (storer) {
            float xq = (q == 0) ? x0 : (q == 1) ? x1 : (q == 2) ? x2 : x3;
            yRow[(long)(s0 + q) * DIMD] = r + Dv * xq;
        }
    }
}

/* ---------------- combine + LN for next layer, one wave per row ---------------- */
__global__ __launch_bounds__(256) void combine_ln_kernel(
    const float* __restrict__ y1, const float* __restrict__ y2,
    const float* __restrict__ z, float* __restrict__ t,
    float* __restrict__ xn, __hip_bfloat16* __restrict__ xn16,
    const float* __restrict__ g, const float* __restrict__ b) {
    int wid = blockIdx.x * 4 + (threadIdx.x >> 6);
    int lane = threadIdx.x & 63;
    long base = (long)wid * DIMD + lane * 4;
    float4 a = *reinterpret_cast<const float4*>(&y1[base]);
    float4 c = *reinterpret_cast<const float4*>(&y2[base]);
    float4 zz = *reinterpret_cast<const float4*>(&z[base]);
    float4 tt = *reinterpret_cast<const float4*>(&t[base]);
    float4 tn;
    {
        float zs;
        zs = zz.x / (1.f + expf(-zz.x)); tn.x = (a.x + c.x) * zs + tt.x;
        zs = zz.y / (1.f + expf(-zz.y)); tn.y = (a.y + c.y) * zs + tt.y;
        zs = zz.z / (1.f + expf(-zz.z)); tn.z = (a.z + c.z) * zs + tt.z;
        zs = zz.w / (1.f + expf(-zz.w)); tn.w = (a.w + c.w) * zs + tt.w;
    }
    *reinterpret_cast<float4*>(&t[base]) = tn;
    float s = tn.x + tn.y + tn.z + tn.w;
    float q = tn.x * tn.x + tn.y * tn.y + tn.z * tn.z + tn.w * tn.w;
#pragma unroll
    for (int m = 32; m >= 1; m >>= 1) {
        s += __shfl_xor(s, m, 64);
        q += __shfl_xor(q, m, 64);
    }
    float mean = s * (1.f / 256.f);
    float var = q * (1.f / 256.f) - mean * mean;
    float rstd = rsqrtf(var + 1e-5f);
    float4 gv = *reinterpret_cast<const float4*>(&g[lane * 4]);
    float4 bv = *reinterpret_cast<const float4*>(&b[lane * 4]);
    float4 o;
    o.x = (tn.x - mean) * rstd * gv.x + bv.x;
    o.y = (tn.y - mean) * rstd * gv.y + bv.y;
    o.z = (tn.z - mean) * rstd * gv.z + bv.z;
    o.w = (tn.w - mean) * rstd * gv.w + bv.w;
    *reinterpret_cast<float4*>(&xn[base]) = o;
    xn16[base + 0] = __float2bfloat16(o.x);
    xn16[base + 1] = __float2bfloat16(o.y);
    xn16[base + 2] = __float2bfloat16(o.z);
    xn16[base + 3] = __float2bfloat16(o.w);
}

/* ---------------- head: pool + LN + linear(1000) + softmax, block per batch ----- */
__global__ __launch_bounds__(256) void head_kernel(
    const float* __restrict__ t, const float* __restrict__ hg,
    const float* __restrict__ hb, const float* __restrict__ hw,
    const float* __restrict__ hbias, float* __restrict__ out) {
    __shared__ float xh[DIMD];
    __shared__ float red[8];
    __shared__ float logits[1000];
    int b = blockIdx.x, tid = threadIdx.x;
    int wv = tid >> 6, ln = tid & 63;

    float s = 0.f;
    const float* tb = t + (long)b * SEQ * DIMD;
    for (int si = 0; si < SEQ; ++si) s += tb[(long)si * DIMD + tid];
    s *= (1.f / (float)SEQ);

    float sum = s, sq = s * s;
#pragma unroll
    for (int m = 32; m >= 1; m >>= 1) {
        sum += __shfl_xor(sum, m, 64);
        sq += __shfl_xor(sq, m, 64);
    }
    if (ln == 0) { red[wv] = sum; red[4 + wv] = sq; }
    __syncthreads();
    float S = red[0] + red[1] + red[2] + red[3];
    float Q = red[4] + red[5] + red[6] + red[7];
    float mean = S * (1.f / 256.f);
    float var = Q * (1.f / 256.f) - mean * mean;
    float rstd = rsqrtf(var + 1e-5f);
    xh[tid] = (s - mean) * rstd * hg[tid] + hb[tid];
    __syncthreads();

    for (int c = tid; c < 1000; c += 256) {
        float acc = hbias[c];
        const float* wr = hw + (long)c * DIMD;
        for (int k = 0; k < DIMD; k += 4) {
            float4 w4 = *reinterpret_cast<const float4*>(&wr[k]);
            acc += xh[k] * w4.x + xh[k + 1] * w4.y + xh[k + 2] * w4.z + xh[k + 3] * w4.w;
        }
        logits[c] = acc;
    }
    __syncthreads();

    float mx = -1e30f;
    for (int c = tid; c < 1000; c += 256) mx = fmaxf(mx, logits[c]);
#pragma unroll
    for (int m = 32; m >= 1; m >>= 1) mx = fmaxf(mx, __shfl_xor(mx, m, 64));
    if (ln == 0) red[wv] = mx;
    __syncthreads();
    mx = fmaxf(fmaxf(red[0], red[1]), fmaxf(red[2], red[3]));
    float se = 0.f;
    for (int c = tid; c < 1000; c += 256) {
        float e = expf(logits[c] - mx);
        logits[c] = e;
        se += e;
    }
#pragma unroll
    for (int m = 32; m >= 1; m >>= 1) se += __shfl_xor(se, m, 64);
    __syncthreads();
    if (ln == 0) red[4 + wv] = se;
    __syncthreads();
    se = red[4] + red[5] + red[6] + red[7];
    float inv = 1.f / se;
    for (int c = tid; c < 1000; c += 256)
        out[b * 1000 + c] = logits[c] * inv;
}

/* ============================== host launcher ============================== */
extern "C" void kernel_launch(void* const* d_in, const int* in_sizes, int n_in,
                              void* d_out, int out_size, void* d_ws, size_t ws_size,
                              hipStream_t stream) {
    const float* x       = (const float*)d_in[0];
    const float* patch_w = (const float*)d_in[1];
    const float* patch_b = (const float*)d_in[2];
    const float* norm_g  = (const float*)d_in[3];
    const float* norm_b  = (const float*)d_in[4];
    const float* proj_w  = (const float*)d_in[5];
    const float* proj_b  = (const float*)d_in[6];
    const float* fconv_w = (const float*)d_in[7];
    const float* fconv_b = (const float*)d_in[8];
    const float* bconv_w = (const float*)d_in[9];
    const float* bconv_b = (const float*)d_in[10];
    const float* dbc_w   = (const float*)d_in[11];
    const float* dt_w    = (const float*)d_in[12];
    const float* dt_b    = (const float*)d_in[13];
    const float* A_log   = (const float*)d_in[14];
    const float* Dp      = (const float*)d_in[15];
    const float* head_g  = (const float*)d_in[16];
    const float* head_b  = (const float*)d_in[17];
    const float* head_w  = (const float*)d_in[18];
    const float* head_bias = (const float*)d_in[19];
    float* out = (float*)d_out; /* reference output dtype is FLOAT32 */

    float* ws = (float*)d_ws;
    const long NTOK = (long)NROWS * DIMD; /* 802816 */
    float* t_buf  = ws;
    float* xn     = ws + NTOK;
    float* z      = ws + 2 * NTOK;
    float* delta1 = ws + 3 * NTOK;
    float* delta2 = ws + 4 * NTOK;
    float* y1     = ws + 5 * NTOK;
    float* y2     = ws + 6 * NTOK;
    float* dbc2   = ws + 7 * NTOK;                 /* 501760 */
    float* xp     = ws + 7 * NTOK + 501760;        /* 2408448 region */
    float* xc1    = xp;
    float* xc2    = xp + NTOK;
    float* dbc1   = xp + 2 * NTOK;
    const long END0 = 7 * NTOK + 501760 + 2408448; /* 8,529,920 f32 */

    /* bf16 region appended after f32 buffers (~12 MB extra; total ws ~44 MiB) */
    __hip_bfloat16* bbase = (__hip_bfloat16*)(ws + END0);
    __hip_bfloat16* xn16   = bbase;
    __hip_bfloat16* z16    = xn16 + NTOK;
    __hip_bfloat16* xc1_16 = z16 + NTOK;
    __hip_bfloat16* xc2_16 = xc1_16 + NTOK;
    __hip_bfloat16* pw16   = xc2_16 + NTOK;        /* 12*65536 */
    __hip_bfloat16* fw16   = pw16 + 12 * 65536;
    __hip_bfloat16* bw16   = fw16 + 12 * 65536;
    __hip_bfloat16* dw16   = bw16 + 12 * 65536;    /* 12*40960 */

    /* one-shot weight conversion (re-done every call; ~6 MB, trivial) */
    cvt_bf16_kernel<<<1024, 256, 0, stream>>>(proj_w, pw16, 12 * 65536);
    cvt_bf16_kernel<<<1024, 256, 0, stream>>>(fconv_w, fw16, 12 * 65536);
    cvt_bf16_kernel<<<1024, 256, 0, stream>>>(bconv_w, bw16, 12 * 65536);
    cvt_bf16_kernel<<<1024, 256, 0, stream>>>(dbc_w, dw16, 12 * 40960);

    /* patch embed (f32, K=768, one-time) */
    gather_kernel<<<(BATCH * SEQ * 768 + 255) / 256, 256, 0, stream>>>(x, xp);
    gemm_kernel<0><<<dim3(49, 4, 1), 256, 0, stream>>>(
        xp, xp, 768, patch_w, patch_w, patch_b, patch_b, t_buf, t_buf, 256,
        NROWS, 256, 768);

    ln_kernel<<<NROWS / 4, 256, 0, stream>>>(t_buf, xn, xn16, norm_g, norm_b);

    for (int L = 0; L < 12; ++L) {
        const float* pb  = proj_b + (long)L * 256;
        const float* fb  = fconv_b + (long)L * 256;
        const float* bb  = bconv_b + (long)L * 256;
        const float* tw  = dt_w + (long)L * 256 * 32;
        const float* tb  = dt_b + (long)L * 256;
        const float* Al  = A_log + (long)L * 256 * 64;
        const float* Dl  = Dp + (long)L * 256;
        int Ln = (L + 1) % 12;
        const float* ng = norm_g + (long)Ln * 256;
        const float* nb = norm_b + (long)Ln * 256;

        /* z = xn @ proj^T + pb   (bf16 MFMA, writes z f32 + z bf16) */
        mfma_gemm<0, 1><<<dim3(49, 4, 1), 256, 0, stream>>>(
            xn16, xn16, pw16 + (long)L * 65536, pw16 + (long)L * 65536,
            pb, pb, z, z, z16, z16, 256, 256);
        /* xc = softplus(z @ conv^T + cb), both directions */
        mfma_gemm<1, 1><<<dim3(49, 4, 2), 256, 0, stream>>>(
            z16, z16, fw16 + (long)L * 65536, bw16 + (long)L * 65536,
            fb, bb, xc1, xc2, xc1_16, xc2_16, 256, 256);
        /* dbc = xc @ dbc_w^T (N=160, f32 out only; feeds delta GEMM + scan B/C) */
        mfma_gemm<0, 0><<<dim3(49, 3, 2), 256, 0, stream>>>(
            xc1_16, xc2_16, dw16 + (long)L * 40960, dw16 + (long)L * 40960,
            nullptr, nullptr, dbc1, dbc2, nullptr, nullptr, 160, 160);
        /* delta = softplus(dbc[:, :32] @ dt_w^T + dt_b)  (kept f32: feeds exp2) */
        gemm_kernel<1><<<dim3(49, 4, 2), 256, 0, stream>>>(
            dbc1, dbc2, 160, tw, tw, tb, tb, delta1, delta2, 256,
            NROWS, 256, 32);
        /* selective scan */
        ssm_kernel<<<dim3(1024, 2), 256, 0, stream>>>(
            xc1, xc2, dbc1, dbc2, delta1, delta2, y1, y2, Al, Dl);
        /* gate + residual + LN for next layer */
        combine_ln_kernel<<<NROWS / 4, 256, 0, stream>>>(
            y1, y2, z, t_buf, xn, xn16, ng, nb);
    }

    head_kernel<<<BATCH, 256, 0, stream>>>(t_buf, head_g, head_b, head_w,
                                           head_bias, out);
}